// Round 15
// baseline (257.955 us; speedup 1.0000x reference)
//
#include <hip/hip_runtime.h>
#include <stdint.h>

#define IN1 16
#define HIDC 10
#define OUT3 16
#define NTYPES 25
#define MAXB 8
#define HSTR 12   // padded row stride (floats) for h1/h2
#define MSTR 16   // msg row stride (floats)
#define CHUNK 32  // edges per wave in phase A (type segments 32-aligned)

#define D1 (IN1 * HIDC)    // 160
#define D2 (HIDC * HIDC)   // 100
#define D3 (HIDC * OUT3)   // 160

// ---------------- init: P tables + zero deg/thist/psum/pcnt + dummy te/ci ----
__global__ __launch_bounds__(256) void init_kernel(
    const float* __restrict__ emb1, const float* __restrict__ wh1,
    const float* __restrict__ bh1, const float* __restrict__ wg1,
    const float* __restrict__ bg1,
    const float* __restrict__ emb2, const float* __restrict__ wh2,
    const float* __restrict__ bh2, const float* __restrict__ wg2,
    const float* __restrict__ bg2,
    const float* __restrict__ emb3, const float* __restrict__ wh3,
    const float* __restrict__ bh3, const float* __restrict__ wg3,
    const float* __restrict__ bg3,
    float4* __restrict__ P1, float4* __restrict__ P2, float4* __restrict__ P3,
    int* __restrict__ deg, int N,
    float* __restrict__ psum, float* __restrict__ pcnt,
    int* __restrict__ thist,
    int4* __restrict__ te, int* __restrict__ ci, int EPAD, int newpath, int B)
{
  int gtid = blockIdx.x * 256 + threadIdx.x;
  int gstr = gridDim.x * 256;
  const int nPrep = NTYPES * (D1 + D2 + D3);
  for (int i = gtid; i < nPrep; i += gstr) {
    const float *emb, *wh, *bh, *wg, *bg; float4* P; int D, k;
    if (i < NTYPES * D1) {
      emb = emb1; wh = wh1; bh = bh1; wg = wg1; bg = bg1; P = P1; D = D1; k = i;
    } else if (i < NTYPES * (D1 + D2)) {
      emb = emb2; wh = wh2; bh = bh2; wg = wg2; bg = bg2; P = P2; D = D2;
      k = i - NTYPES * D1;
    } else {
      emb = emb3; wh = wh3; bh = bh3; wg = wg3; bg = bg3; P = P3; D = D3;
      k = i - NTYPES * (D1 + D2);
    }
    int j = k - (k / D) * D;
    float e = emb[k];
    float4 p;
    p.x = fmaf(e, wh[j],     wg[j]);
    p.y = fmaf(e, wh[D + j], wg[D + j]);
    p.z = fmaf(e, bh[j],     bg[j]);
    p.w = 0.f;
    P[k] = p;
  }
  for (int i = gtid; i < N; i += gstr) deg[i] = 0;
  for (int i = gtid; i < B * 16; i += gstr) psum[i] = 0.f;
  for (int i = gtid; i < B; i += gstr) pcnt[i] = 0.f;
  if (gtid < NTYPES) thist[gtid] = 0;
  if (newpath) {   // dummy-fill type-sorted arrays (padding slots stay dummy)
    for (int i = gtid; i < EPAD; i += gstr) {
      te[i] = make_int4(0, 0, 0, 0);
      ci[i] = -1;
    }
  }
}

// ---------------- hist: dst-degree rank + per-block LDS type histogram -------
__global__ __launch_bounds__(256) void hist_kernel(
    const int* __restrict__ edst, const int* __restrict__ et,
    int* __restrict__ deg, int* __restrict__ pos,
    int* __restrict__ thist, int* __restrict__ tpos, int E) {
  __shared__ int s_cnt[NTYPES];
  __shared__ int s_base[NTYPES];
  int tid = threadIdx.x;
  if (tid < NTYPES) s_cnt[tid] = 0;
  __syncthreads();
  int e = blockIdx.x * 256 + tid;
  int t = 0, lr = 0, p = 0;
  if (e < E) {
    p = atomicAdd(&deg[edst[e]], 1);
    t = et[e];
    lr = atomicAdd(&s_cnt[t], 1);
  }
  __syncthreads();
  if (tid < NTYPES && s_cnt[tid] > 0) s_base[tid] = atomicAdd(&thist[tid], s_cnt[tid]);
  __syncthreads();
  if (e < E) {
    pos[e] = p;
    tpos[e] = s_base[t] + lr;
  }
}

// ---------------- per-1024-chunk local scan + chunk sum ----------------------
__global__ __launch_bounds__(256) void scan_part_kernel(const int* __restrict__ deg,
                                                        int* __restrict__ row_ptr,
                                                        int* __restrict__ bsum, int N) {
  __shared__ int wsums[4];
  int tid = threadIdx.x, lane = tid & 63, wid = tid >> 6;
  int idx0 = (blockIdx.x * 256 + tid) * 4;
  int4 v = make_int4(0, 0, 0, 0);
  if (idx0 < N)     v.x = deg[idx0];
  if (idx0 + 1 < N) v.y = deg[idx0 + 1];
  if (idx0 + 2 < N) v.z = deg[idx0 + 2];
  if (idx0 + 3 < N) v.w = deg[idx0 + 3];
  int s = v.x + v.y + v.z + v.w;
  int x = s;
  #pragma unroll
  for (int off = 1; off < 64; off <<= 1) {
    int y = __shfl_up(x, off);
    if (lane >= off) x += y;
  }
  if (lane == 63) wsums[wid] = x;
  __syncthreads();
  int wpre = 0;
  #pragma unroll
  for (int w = 0; w < 4; ++w) if (w < wid) wpre += wsums[w];
  int excl = x - s + wpre;
  if (idx0 < N)     row_ptr[idx0]     = excl;
  if (idx0 + 1 < N) row_ptr[idx0 + 1] = excl + v.x;
  if (idx0 + 2 < N) row_ptr[idx0 + 2] = excl + v.x + v.y;
  if (idx0 + 3 < N) row_ptr[idx0 + 3] = excl + v.x + v.y + v.z;
  if (tid == 255) bsum[blockIdx.x] = excl + s;
}

// ------ fused: chunk-offset scan+add; block0/wave1 builds 32-aligned toff ----
__global__ __launch_bounds__(256) void scan_add2_kernel(int* __restrict__ row_ptr,
                                                        const int* __restrict__ bsum,
                                                        const int* __restrict__ thist,
                                                        int* __restrict__ toff,
                                                        int N, int chunks) {
  __shared__ int s_off;
  int c = blockIdx.x, tid = threadIdx.x;
  if (tid < 64) {
    int v = (tid < c) ? bsum[tid] : 0;
    #pragma unroll
    for (int off = 32; off >= 1; off >>= 1) v += __shfl_xor(v, off);
    if (tid == 0) s_off = v;
  }
  if (c == 0 && tid >= 64 && tid < 128) {   // wave 1: 32-aligned type offsets
    int l = tid - 64;
    int b = (l < NTYPES) ? ((thist[l] + CHUNK - 1) & ~(CHUNK - 1)) : 0;
    int x = b;
    #pragma unroll
    for (int off = 1; off < 32; off <<= 1) {
      int y = __shfl_up(x, off);
      if (l >= off) x += y;
    }
    if (l < NTYPES) toff[l] = x - b;
    if (l == NTYPES - 1) toff[NTYPES] = x;
  }
  __syncthreads();
  int off = s_off;
  int base = c * 1024 + tid * 4;
  #pragma unroll
  for (int j = 0; j < 4; ++j) {
    int idx = base + j;
    if (idx < N) row_ptr[idx] += off;
  }
  if (c == chunks - 1 && tid == 0) row_ptr[N] = off + bsum[c];
}

// ---------------- new-path permute: type-sorted records + CSR index ----------
__global__ __launch_bounds__(256) void permuteT_kernel(
    const int* __restrict__ edst, const int* __restrict__ esrc,
    const int* __restrict__ et, const float2* __restrict__ ef,
    const int* __restrict__ row_ptr, const int* __restrict__ pos,
    const int* __restrict__ tpos, const int* __restrict__ toff,
    int4* __restrict__ te, int* __restrict__ ci, int E) {
  int e = blockIdx.x * blockDim.x + threadIdx.x;
  if (e >= E) return;
  int t = et[e];
  int slot = toff[t] + tpos[e];
  float2 f = ef[e];
  te[slot] = make_int4(esrc[e], t, __float_as_int(f.x), __float_as_int(f.y));
  ci[slot] = row_ptr[edst[e]] + pos[e];
}

// ---------------- old-path permute: CSR-ordered edge records (fallback) ------
__global__ __launch_bounds__(256) void permute_kernel(
    const int* __restrict__ edst, const int* __restrict__ esrc,
    const int* __restrict__ et, const float2* __restrict__ ef,
    const int* __restrict__ row_ptr, const int* __restrict__ pos,
    int4* __restrict__ edges, int E) {
  int e = blockIdx.x * blockDim.x + threadIdx.x;
  if (e >= E) return;
  int idx = row_ptr[edst[e]] + pos[e];
  float2 f = ef[e];
  edges[idx] = make_int4(esrc[e], et[e], __float_as_int(f.x), __float_as_int(f.y));
}

// ---------------- Phase A: edge-parallel msg, coefficients in REGISTERS ------
// wave = CHUNK consecutive type-sorted edges (one type); lane = es*16 + oc.
// Zero LDS in the hot loop (the R7-R14 kernels were LDS-pipe-bound at
// 16 ds_read_b128/edge-iter; here P lives in 3*IN_C VGPRs per lane).
template<int IN_C, int O, int XS>
__global__ __launch_bounds__(256) void edgeA_kernel(
    const float* __restrict__ xin,      // [*, XS]
    const int4* __restrict__ te,        // type-sorted {src, t, f0, f1}
    const int* __restrict__ ci,         // CSR position (-1 = padding)
    const float4* __restrict__ Pg,      // [25*D] packed {P0,P1,P2,-}
    float* __restrict__ msg,            // [E, MSTR]
    const int* __restrict__ toff)       // [26]
{
  int tid = threadIdx.x;
  int lane = tid & 63;
  int wv = blockIdx.x * 4 + (tid >> 6);
  int base = wv * CHUNK;
  if (base >= toff[NTYPES]) return;
  int oc = lane & 15;
  int es = lane >> 4;
  int ocl = (O == 16) ? oc : ((oc < O) ? oc : 0);
  int t = te[base].y;                   // first slot of a chunk is always real
  float c0[IN_C], c1[IN_C], c2[IN_C];
  const float4* __restrict__ pb = Pg + t * (IN_C * O) + ocl;
  #pragma unroll
  for (int i = 0; i < IN_C; ++i) {
    float4 p = pb[i * O];
    c0[i] = p.x; c1[i] = p.y; c2[i] = p.z;
  }
  #pragma unroll 1
  for (int it = 0; it < CHUNK / 4; ++it) {
    int slot = base + it * 4 + es;
    int4 r = te[slot];
    int cidx = ci[slot];
    float f0 = __int_as_float(r.z), f1 = __int_as_float(r.w);
    const float* __restrict__ xr = xin + (size_t)(unsigned)r.x * XS;
    float acc = 0.f;
    #pragma unroll
    for (int q = 0; q < IN_C / 4; ++q) {
      float4 xq = ((const float4*)xr)[q];
      int i0 = 4 * q;
      acc = fmaf(xq.x, fmaxf(fmaf(f0, c0[i0+0], fmaf(f1, c1[i0+0], c2[i0+0])), 0.f), acc);
      acc = fmaf(xq.y, fmaxf(fmaf(f0, c0[i0+1], fmaf(f1, c1[i0+1], c2[i0+1])), 0.f), acc);
      acc = fmaf(xq.z, fmaxf(fmaf(f0, c0[i0+2], fmaf(f1, c1[i0+2], c2[i0+2])), 0.f), acc);
      acc = fmaf(xq.w, fmaxf(fmaf(f0, c0[i0+3], fmaf(f1, c1[i0+3], c2[i0+3])), 0.f), acc);
    }
    if constexpr (IN_C % 4 == 2) {
      float2 xq = ((const float2*)xr)[IN_C / 2 - 1];
      acc = fmaf(xq.x, fmaxf(fmaf(f0, c0[IN_C-2], fmaf(f1, c1[IN_C-2], c2[IN_C-2])), 0.f), acc);
      acc = fmaf(xq.y, fmaxf(fmaf(f0, c0[IN_C-1], fmaf(f1, c1[IN_C-1], c2[IN_C-1])), 0.f), acc);
    }
    if (cidx >= 0 && oc < O) msg[(size_t)cidx * MSTR + oc] = acc;
  }
}

// ---------------- Phase B: streaming segment-sum + mean/root/bias/relu -------
template<int IN_C, int O, int XS, bool POOL, int BS>
__global__ __launch_bounds__(BS) void nodeB_kernel(
    const float* __restrict__ xin,      // [N, XS] (for root term)
    const float* __restrict__ msg,      // [E, MSTR] in CSR order
    const int* __restrict__ row_ptr,
    const float* __restrict__ root, const float* __restrict__ bias,
    float* __restrict__ hout, const int* __restrict__ ctype,
    const int* __restrict__ bids, float* __restrict__ pcnt, int N, int B)
{
  constexpr int NPB = BS / 16;
  __shared__ float s_psum[POOL ? (MAXB * 16) : 1];
  __shared__ float s_pcnt[POOL ? MAXB : 1];
  int tid = threadIdx.x;
  if (POOL) {
    for (int i = tid; i < MAXB * 16; i += BS) s_psum[i] = 0.f;
    for (int i = tid; i < MAXB; i += BS) s_pcnt[i] = 0.f;
    __syncthreads();
  }
  int nl = tid >> 4;
  int o = tid & 15;
  int n = blockIdx.x * NPB + nl;
  float acc = 0.f;
  int start = 0, end = 0;
  if (n < N) { start = row_ptr[n]; end = row_ptr[n + 1]; }
  for (int e = start; e < end; ++e) acc += msg[(size_t)e * MSTR + o];

  if (n < N && o < O) {
    float inv = 1.0f / fmaxf((float)(end - start), 1.0f);
    float v = fmaf(acc, inv, bias[o]);
    const float* __restrict__ xr = xin + (size_t)n * XS;
    #pragma unroll
    for (int i = 0; i < IN_C; ++i) v = fmaf(xr[i], root[i * O + o], v);
    v = fmaxf(v, 0.f);
    if (!POOL) {
      hout[(size_t)n * HSTR + o] = v;
    } else {
      if (ctype[n] == 1) {
        int b = bids[n];
        atomicAdd(&s_psum[b * 16 + o], v);
        if (o == 0) atomicAdd(&s_pcnt[b], 1.0f);
      }
    }
  }
  if (POOL) {
    __syncthreads();
    for (int i = tid; i < B * 16; i += BS) {
      float v = s_psum[i];
      if (v != 0.f) atomicAdd(&hout[i], v);
    }
    for (int i = tid; i < B; i += BS) {
      float c = s_pcnt[i];
      if (c != 0.f) atomicAdd(&pcnt[i], c);
    }
  }
}

// ---------------- fallback layer kernel (R14-verbatim, proven 252us) ---------
template<int IN_C, int O, int XS, bool POOL, int BS>
__global__ __launch_bounds__(BS) void layer_kernel(
    const float* __restrict__ xin, const int4* __restrict__ edges,
    const int* __restrict__ row_ptr, const float4* __restrict__ Pg,
    const float* __restrict__ root, const float* __restrict__ bias,
    float* __restrict__ hout, const int* __restrict__ ctype,
    const int* __restrict__ bids, float* __restrict__ pcnt, int N, int B)
{
  constexpr int D = IN_C * O;
  constexpr int TSTR = D + 1;
  constexpr int NPW = 4;
  __shared__ float4 s_P[NTYPES * TSTR];
  __shared__ float s_psum[POOL ? (MAXB * 16) : 1];
  __shared__ float s_pcnt[POOL ? MAXB : 1];
  int tid = threadIdx.x;
  for (int k = tid; k < NTYPES * D; k += BS) {
    int t = k / D, j = k - t * D;
    s_P[t * TSTR + j] = Pg[k];
  }
  if (POOL) {
    for (int i = tid; i < MAXB * 16; i += BS) s_psum[i] = 0.f;
    for (int i = tid; i < MAXB; i += BS) s_pcnt[i] = 0.f;
  }
  __syncthreads();
  int lane = tid & 63;
  int wv = tid >> 6;
  int o = lane & 15;
  int es = lane >> 4;
  int oc = (O == 16) ? o : ((o < O) ? o : 0);
  int nb = (blockIdx.x * (BS / 64) + wv) * NPW;
  float accs = 0.f;
  int degs = 0;
  #pragma unroll
  for (int s = 0; s < NPW; ++s) {
    int n = nb + s;
    float acc = 0.f;
    int start = 0, end = 0;
    if (n < N) { start = row_ptr[n]; end = row_ptr[n + 1]; }
    for (int e = start + es; e < end; e += 4) {
      int4 r = edges[e];
      float f0 = __int_as_float(r.z), f1 = __int_as_float(r.w);
      const float4* __restrict__ pb = s_P + r.y * TSTR + oc;
      const float* __restrict__ xr = xin + (size_t)r.x * XS;
      #pragma unroll
      for (int q = 0; q < IN_C / 4; ++q) {
        float4 xq = ((const float4*)xr)[q];
        float4 p0 = pb[(4 * q + 0) * O];
        float4 p1 = pb[(4 * q + 1) * O];
        float4 p2 = pb[(4 * q + 2) * O];
        float4 p3 = pb[(4 * q + 3) * O];
        acc = fmaf(xq.x, fmaxf(fmaf(f0, p0.x, fmaf(f1, p0.y, p0.z)), 0.f), acc);
        acc = fmaf(xq.y, fmaxf(fmaf(f0, p1.x, fmaf(f1, p1.y, p1.z)), 0.f), acc);
        acc = fmaf(xq.z, fmaxf(fmaf(f0, p2.x, fmaf(f1, p2.y, p2.z)), 0.f), acc);
        acc = fmaf(xq.w, fmaxf(fmaf(f0, p3.x, fmaf(f1, p3.y, p3.z)), 0.f), acc);
      }
      if constexpr (IN_C % 4 == 2) {
        float2 xq = ((const float2*)xr)[IN_C / 2 - 1];
        float4 p0 = pb[(IN_C - 2) * O];
        float4 p1 = pb[(IN_C - 1) * O];
        acc = fmaf(xq.x, fmaxf(fmaf(f0, p0.x, fmaf(f1, p0.y, p0.z)), 0.f), acc);
        acc = fmaf(xq.y, fmaxf(fmaf(f0, p1.x, fmaf(f1, p1.y, p1.z)), 0.f), acc);
      }
    }
    acc += __shfl_xor(acc, 16);
    acc += __shfl_xor(acc, 32);
    if (es == s) { accs = acc; degs = end - start; }
  }
  int n = nb + es;
  if (n < N && o < O) {
    float inv = 1.0f / fmaxf((float)degs, 1.0f);
    float v = fmaf(accs, inv, bias[o]);
    const float* __restrict__ xr = xin + (size_t)n * XS;
    #pragma unroll
    for (int i = 0; i < IN_C; ++i) v = fmaf(xr[i], root[i * O + o], v);
    v = fmaxf(v, 0.f);
    if (!POOL) {
      hout[(size_t)n * HSTR + o] = v;
    } else {
      if (ctype[n] == 1) {
        int b = bids[n];
        atomicAdd(&s_psum[b * 16 + o], v);
        if (o == 0) atomicAdd(&s_pcnt[b], 1.0f);
      }
    }
  }
  if (POOL) {
    __syncthreads();
    for (int i = tid; i < B * 16; i += BS) {
      float v = s_psum[i];
      if (v != 0.f) atomicAdd(&hout[i], v);
    }
    for (int i = tid; i < B; i += BS) {
      float c = s_pcnt[i];
      if (c != 0.f) atomicAdd(&pcnt[i], c);
    }
  }
}

__global__ __launch_bounds__(256) void finalize_kernel(
    const float* __restrict__ psum, const float* __restrict__ pcnt,
    float* __restrict__ out, int B) {
  int i = blockIdx.x * blockDim.x + threadIdx.x;
  if (i >= B * OUT3) return;
  int b = i / OUT3;
  out[i] = psum[i] / fmaxf(pcnt[b], 1.0f);
}

// ---------------- launch ----------------
extern "C" void kernel_launch(void* const* d_in, const int* in_sizes, int n_in,
                              void* d_out, int out_size, void* d_ws, size_t ws_size,
                              hipStream_t stream)
{
  const float* x     = (const float*)d_in[0];
  const float* ef    = (const float*)d_in[1];
  const int*   et    = (const int*)d_in[2];
  const int*   esrc  = (const int*)d_in[3];
  const int*   edst  = (const int*)d_in[4];
  const int*   ctype = (const int*)d_in[5];
  const int*   bids  = (const int*)d_in[6];
  const float* emb1 = (const float*)d_in[8];
  const float* wh1  = (const float*)d_in[9];
  const float* bh1  = (const float*)d_in[10];
  const float* wg1  = (const float*)d_in[11];
  const float* bg1  = (const float*)d_in[12];
  const float* root1= (const float*)d_in[13];
  const float* bias1= (const float*)d_in[14];
  const float* emb2 = (const float*)d_in[15];
  const float* wh2  = (const float*)d_in[16];
  const float* bh2  = (const float*)d_in[17];
  const float* wg2  = (const float*)d_in[18];
  const float* bg2  = (const float*)d_in[19];
  const float* root2= (const float*)d_in[20];
  const float* bias2= (const float*)d_in[21];
  const float* emb3 = (const float*)d_in[22];
  const float* wh3  = (const float*)d_in[23];
  const float* bh3  = (const float*)d_in[24];
  const float* wg3  = (const float*)d_in[25];
  const float* bg3  = (const float*)d_in[26];
  const float* root3= (const float*)d_in[27];
  const float* bias3= (const float*)d_in[28];

  const int N = in_sizes[0] / IN1;
  const int E = in_sizes[2];
  const int B = out_size / OUT3;
  const int EPAD = E + NTYPES * CHUNK;

  // workspace layout
  int4* te      = (int4*)d_ws;                       // EPAD recs (CSR edges in fallback)
  int*  ci      = (int*)(te + EPAD);                 // EPAD
  int*  deg     = ci + EPAD;                         // N
  int*  row_ptr = deg + N;                           // N+1
  int*  bsum    = row_ptr + (N + 1);                 // <=64
  int*  thist   = bsum + 64;                         // 25 (pad 32)
  int*  toff    = thist + 32;                        // 26 (pad 32)
  uintptr_t pp  = ((uintptr_t)(toff + 32) + 15) & ~(uintptr_t)15;
  float4* P1    = (float4*)pp;                       // 25*D1
  float4* P2    = P1 + NTYPES * D1;                  // 25*D2
  float4* P3    = P2 + NTYPES * D2;                  // 25*D3
  float* h1     = (float*)(P3 + NTYPES * D3);        // N*HSTR
  float* h2     = h1 + (size_t)N * HSTR;             // N*HSTR
  float* psum   = h2 + (size_t)N * HSTR;             // B*16
  float* pcnt   = psum + (size_t)B * 16;             // B
  uintptr_t mp  = ((uintptr_t)(pcnt + B) + 15) & ~(uintptr_t)15;
  int*  pos     = (int*)mp;                          // E (dead after permute)
  int*  tpos    = pos + E;                           // E (dead after permute)
  float* msg    = (float*)mp;                        // E*MSTR (reuses pos/tpos)

  size_t req_new = (mp - (uintptr_t)d_ws) + (size_t)E * MSTR * 4;
  const bool newpath = (req_new <= ws_size);

  const int nChunk = (N + 1023) / 1024;

  init_kernel<<<512, 256, 0, stream>>>(
      emb1, wh1, bh1, wg1, bg1, emb2, wh2, bh2, wg2, bg2,
      emb3, wh3, bh3, wg3, bg3, P1, P2, P3, deg, N, psum, pcnt,
      thist, te, ci, EPAD, newpath ? 1 : 0, B);
  hist_kernel<<<(E + 255) / 256, 256, 0, stream>>>(edst, et, deg, pos, thist, tpos, E);
  scan_part_kernel<<<nChunk, 256, 0, stream>>>(deg, row_ptr, bsum, N);
  scan_add2_kernel<<<nChunk, 256, 0, stream>>>(row_ptr, bsum, thist, toff, N, nChunk);

  if (newpath) {
    permuteT_kernel<<<(E + 255) / 256, 256, 0, stream>>>(
        edst, esrc, et, (const float2*)ef, row_ptr, pos, tpos, toff, te, ci, E);

    const int gA = ((EPAD + CHUNK - 1) / CHUNK + 3) / 4;  // 4 waves/block
    const int gB = (N + 15) / 16;
    edgeA_kernel<IN1, HIDC, IN1><<<gA, 256, 0, stream>>>(x, te, ci, P1, msg, toff);
    nodeB_kernel<IN1, HIDC, IN1, false, 256><<<gB, 256, 0, stream>>>(
        x, msg, row_ptr, root1, bias1, h1, nullptr, nullptr, nullptr, N, B);
    edgeA_kernel<HIDC, HIDC, HSTR><<<gA, 256, 0, stream>>>(h1, te, ci, P2, msg, toff);
    nodeB_kernel<HIDC, HIDC, HSTR, false, 256><<<gB, 256, 0, stream>>>(
        h1, msg, row_ptr, root2, bias2, h2, nullptr, nullptr, nullptr, N, B);
    edgeA_kernel<HIDC, OUT3, HSTR><<<gA, 256, 0, stream>>>(h2, te, ci, P3, msg, toff);
    const int gB3 = (N + 63) / 64;
    nodeB_kernel<HIDC, OUT3, HSTR, true, 1024><<<gB3, 1024, 0, stream>>>(
        h2, msg, row_ptr, root3, bias3, psum, ctype, bids, pcnt, N, B);
  } else {
    permute_kernel<<<(E + 255) / 256, 256, 0, stream>>>(
        edst, esrc, et, (const float2*)ef, row_ptr, pos, te, E);
    const int g512 = (N + 31) / 32;
    layer_kernel<IN1, HIDC, IN1, false, 512><<<g512, 512, 0, stream>>>(
        x, te, row_ptr, P1, root1, bias1, h1, nullptr, nullptr, nullptr, N, B);
    layer_kernel<HIDC, HIDC, HSTR, false, 512><<<g512, 512, 0, stream>>>(
        h1, te, row_ptr, P2, root2, bias2, h2, nullptr, nullptr, nullptr, N, B);
    const int g1024 = (N + 63) / 64;
    layer_kernel<HIDC, OUT3, HSTR, true, 1024><<<g1024, 1024, 0, stream>>>(
        h2, te, row_ptr, P3, root3, bias3, psum, ctype, bids, pcnt, N, B);
  }

  finalize_kernel<<<1, 256, 0, stream>>>(psum, pcnt, (float*)d_out, B);
}